// Round 12
// baseline (68.189 us; speedup 1.0000x reference)
//
#include <hip/hip_runtime.h>
#include <stdint.h>

typedef unsigned int u32;
typedef unsigned long long u64;

#define HW (1024*1024)
#define KTOP 500
#define CAP 8192u
#define POST_MAX 83
#define DELTA_THR 9728u     // v > 1 - 9728*2^-24 ~ 0.99942; E[count/slice] ~ 580

// workspace byte offsets
#define WS_CNT2  0          // u32[16*128] = 8 KB (every slot written every run)
#define WS_CAND  32768      // uint2[16*8192] -> ends 1081344

// out layout (floats): boxes[0,36000) scores[36000,40000) clses[40000,44000)
// valid[44000,48000) keep[48000,52000)

// ---------------- K1: streaming collect, fixed per-chunk slots, NO atomics ---
__global__ __launch_bounds__(256) void k1_collect(const float* __restrict__ heat,
                                                  u32* cnt2, uint2* cand){
  __shared__ uint2 lbuf[64];
  __shared__ u32 lcnt;
  int s     = blockIdx.x >> 7;   // 16 slices x 128 chunks
  int chunk = blockIdx.x & 127;
  int tid   = threadIdx.x;
  if (tid == 0) lcnt = 0;
  __syncthreads();
  const float4* hp = (const float4*)(heat + (size_t)s*HW + (size_t)chunk*8192);
  float4 v[8];
  #pragma unroll
  for (int i = 0; i < 8; ++i) v[i] = hp[i*256 + tid];
  #pragma unroll
  for (int i = 0; i < 8; ++i){
    u32 idx0 = (u32)chunk*8192u + (u32)(i*256 + tid)*4u;
    float vals[4] = {v[i].x, v[i].y, v[i].z, v[i].w};
    #pragma unroll
    for (int c = 0; c < 4; ++c){
      u32 bits  = __float_as_uint(vals[c]);
      u32 delta = 0x3F800000u - bits;         // ulps below 1.0
      if (delta < DELTA_THR){                 // E ~ 4.8 per chunk
        u32 p = atomicAdd(&lcnt, 1u);         // LDS atomic only
        if (p < 64u) lbuf[p] = make_uint2(bits, idx0 + (u32)c);
      }
    }
  }
  __syncthreads();
  u32 n = lcnt;
  u32 stored = (n < 64u) ? n : 64u;
  if (tid < stored) cand[(size_t)s*CAP + (u32)chunk*64u + tid] = lbuf[tid];
  if (tid == 0) cnt2[s*128 + chunk] = stored | ((n > 64u) ? 0x80000000u : 0u);
}

// ---------------- KT: rank both slices + merge + decode + NMS (one launch) ---
__global__ __launch_bounds__(1024) void kT_tail(const float* __restrict__ heat,
                                                const u32* __restrict__ cnt2,
                                                uint2* cand,
                                                const float* __restrict__ reg,
                                                const float* __restrict__ rots,
                                                const float* __restrict__ rotc,
                                                const float* __restrict__ hei,
                                                const float* __restrict__ dim,
                                                const float* __restrict__ vel,
                                                float* out){
  __shared__ __align__(16) u64 lkey[CAP];     // 64 KB; tail buffers alias it later
  __shared__ uint2 sortedL[2][512];           // 8 KB, live across phases
  __shared__ u32 tmpc[128];
  __shared__ u32 cofs[129];
  __shared__ u32 lhist[256];
  __shared__ u32 lc;
  __shared__ int t2s;
  __shared__ u32 meta_sh;
  __shared__ int wsum[16];
  __shared__ u64 keepw[8];
  int b = blockIdx.x, t = threadIdx.x;

  // ================= stage A: rank both slices sequentially ==================
  for (int sl = 0; sl < 2; ++sl){
    int s = 2*b + sl;
    if (t < 128) tmpc[t] = cnt2[s*128 + t];
    __syncthreads();
    if (t == 0){
      u32 tot = 0, ov = 0;
      for (int c = 0; c < 128; ++c){
        u32 w = tmpc[c];
        ov |= (w >> 31);
        cofs[c] = tot;
        tot += (w & 0x7FFFFFFFu);
      }
      cofs[128] = tot;
      meta_sh = tot | (ov << 31);
    }
    __syncthreads();
    u32 total = meta_sh & 0x7FFFFFFFu;
    bool fb = ((meta_sh >> 31) != 0u) || (total < (u32)KTOP);
    u32 n;

    if (!fb){
      n = total;
      // gather per-chunk runs into compact key array (value desc, idx asc)
      for (u32 i = t; i < CAP; i += 1024){
        u32 c = i >> 6, j = i & 63u;
        u32 cnt_c = cofs[c+1] - cofs[c];
        if (j < cnt_c){
          uint2 cv = cand[(size_t)s*CAP + i];
          lkey[cofs[c] + j] = ((u64)(~cv.x) << 32) | (u64)cv.y;
        }
      }
      __syncthreads();
    } else {
      // ---- exactness fallback (never taken on this data): hist + recollect --
      if (t < 256) lhist[t] = 0;
      if (t == 0) lc = 0;
      __syncthreads();
      const float4* hp = (const float4*)(heat + (size_t)s*HW);
      for (int it = 0; it < 256; ++it){
        float4 v = hp[it*1024 + t];
        #pragma unroll
        for (int c = 0; c < 4; ++c){
          float val = (c==0)?v.x:(c==1)?v.y:(c==2)?v.z:v.w;
          u32 bits  = __float_as_uint(val);
          u32 delta = 0x3F800000u - bits;
          u32 bin   = delta >> 16; if (bin > 255u) bin = 255u;
          atomicAdd(&lhist[bin], 1u);
        }
      }
      __syncthreads();
      if (t == 0){
        u32 cum = 0; u32 b1 = 255u;
        for (u32 bb = 0; bb < 256u; ++bb){
          cum += lhist[bb];
          if (cum >= (u32)KTOP){ b1 = bb; break; }
        }
        t2s = (int)(0x3F800000u - ((b1 + 1u) << 16) + 1u);
      }
      __syncthreads();
      int t2 = t2s;
      for (int it = 0; it < 256; ++it){
        float4 v = hp[it*1024 + t];
        u32 idx0 = (u32)(it*1024 + t)*4u;
        #pragma unroll
        for (int c = 0; c < 4; ++c){
          float val = (c==0)?v.x:(c==1)?v.y:(c==2)?v.z:v.w;
          int bits = (int)__float_as_uint(val);   // signed cmp excludes negatives
          if (bits >= t2){
            u32 p = atomicAdd(&lc, 1u);
            if (p < CAP) cand[(size_t)s*CAP + p] = make_uint2((u32)bits, idx0 + (u32)c);
          }
        }
      }
      __syncthreads();
      n = (lc < CAP) ? lc : CAP;
      for (u32 i = t; i < n; i += 1024){
        uint2 cv = cand[(size_t)s*CAP + i];
        lkey[i] = ((u64)(~cv.x) << 32) | (u64)cv.y;
      }
      __syncthreads();
    }

    // ---- rank-by-count: rank = #{key' < key}; write top-512 to LDS ----------
    const ulonglong2* lk2 = (const ulonglong2*)lkey;
    for (u32 me = t; me < n; me += 1024){
      u64 k0 = lkey[me];
      u32 r = 0;
      u32 half = n >> 1;
      for (u32 j = 0; j < half; ++j){
        ulonglong2 kk = lk2[j];               // LDS broadcast read
        r += (kk.x < k0) ? 1u : 0u;
        r += (kk.y < k0) ? 1u : 0u;
      }
      if (n & 1u) r += (lkey[n-1] < k0) ? 1u : 0u;
      if (r < 512u)
        sortedL[sl][r] = make_uint2(~(u32)(k0 >> 32), (u32)k0);
    }
    __syncthreads();   // lkey dead after last slice; cofs/tmpc reusable
  }

  // ================= stage B: tail (buffers alias lkey) ======================
  char* big = (char*)lkey;
  u64*    k2a   = (u64*)   big;              // 4 KB
  u64*    k2b   = (u64*)  (big + 4096);      // 4 KB
  uint2*  fin   = (uint2*)(big + 8192);      // 4 KB  .x=score bits .y=idx|cls<<20
  float*  xo    = (float*)(big + 12288);     // 2 KB
  float*  yo    = (float*)(big + 14336);     // 2 KB
  float2* pts   = (float2*)(big + 16384);    // 4 KB
  int*    order = (int*)  (big + 20480);     // 2 KB
  int*    vld   = (int*)  (big + 22528);     // 2 KB
  u32*    ordvl = (u32*)  (big + 24576);     // 2 KB

  // ---- phase 1: level-2 keys (score desc, concat-pos asc)
  uint2 mye = make_uint2(0u, 0u);
  if (t < 512){
    mye = sortedL[0][t];
    k2a[t] = ((u64)(~mye.x) << 32) | (u64)t;
  } else {
    int p = t - 512;
    mye = sortedL[1][p];
    k2b[p] = ((u64)(~mye.x) << 32) | (u64)(KTOP + p);
  }
  if (t < 8) keepw[t] = 0ull;
  __syncthreads();

  // ---- phase 2: merged rank = own rank + lower_bound in other list
  if (t < KTOP){
    u64 K = k2a[t];
    int lo = 0, hi = KTOP;
    while (lo < hi){ int mid = (lo + hi) >> 1; if (k2b[mid] < K) lo = mid + 1; else hi = mid; }
    int m = t + lo;
    if (m < KTOP){
      fin[m] = make_uint2(mye.x, mye.y & 0xFFFFFu);
      out[36000 + b*KTOP + m] = __uint_as_float(mye.x);
      out[40000 + b*KTOP + m] = 0.0f;
    }
  } else if (t >= 512 && t < 512 + KTOP){
    int p = t - 512;
    u64 K = k2b[p];
    int lo = 0, hi = KTOP;
    while (lo < hi){ int mid = (lo + hi) >> 1; if (k2a[mid] < K) lo = mid + 1; else hi = mid; }
    int m = p + lo;
    if (m < KTOP){
      fin[m] = make_uint2(mye.x, (mye.y & 0xFFFFFu) | (1u << 20));
      out[36000 + b*KTOP + m] = __uint_as_float(mye.x);
      out[40000 + b*KTOP + m] = 1.0f;
    }
  }
  __syncthreads();

  // ---- phase 3: gather + decode + valid
  float x = 0.f, y = 0.f; int v = 0;
  if (t < KTOP){
    uint2 e = fin[t];
    u32 ind = e.y & 0xFFFFFu;
    float mysc = __uint_as_float(e.x);
    float xs0 = (float)(ind & 1023u);
    float ys0 = (float)(ind >> 10);
    size_t bb = (size_t)b;
    float r0  = reg [(bb*2 + 0)*HW + ind];
    float r1  = reg [(bb*2 + 1)*HW + ind];
    float sn  = rots[ bb       *HW + ind];
    float cs  = rotc[ bb       *HW + ind];
    float he  = hei [ bb       *HW + ind];
    float d0  = dim [(bb*3 + 0)*HW + ind];
    float d1  = dim [(bb*3 + 1)*HW + ind];
    float d2v = dim [(bb*3 + 2)*HW + ind];
    float v0  = vel [(bb*2 + 0)*HW + ind];
    float v1  = vel [(bb*2 + 1)*HW + ind];
    x = xs0 + r0; y = ys0 + r1;
    float rot = atan2f(sn, cs);
    float* bx = out + (size_t)(b*KTOP + t)*9;
    bx[0]=x; bx[1]=y; bx[2]=he; bx[3]=d0; bx[4]=d1; bx[5]=d2v; bx[6]=rot; bx[7]=v0; bx[8]=v1;
    v = ((x >= -100.0f) && (x <= 1124.0f) &&
         (y >= -100.0f) && (y <= 1124.0f) &&
         (he >= -10.0f) && (he <= 10.0f) && (mysc > 0.1f)) ? 1 : 0;
    out[44000 + b*KTOP + t] = v ? 1.0f : 0.0f;
  }
  if (t < 512){ xo[t] = x; yo[t] = y; vld[t] = v; }

  // ---- phase 4: 1-barrier ballot scan, stable valid-first partition
  u64 bm = __ballot(v != 0);
  int lane = t & 63, wv = t >> 6;
  if (lane == 0) wsum[wv] = __popcll(bm);
  __syncthreads();
  int off = 0, nValid = 0;
  #pragma unroll
  for (int w2 = 0; w2 < 8; ++w2){
    int sv = wsum[w2];
    nValid += sv;
    if (w2 < wv) off += sv;
  }
  int incl = off + __popcll(bm & ((~0ull) >> (63 - lane)));
  if (t < KTOP){
    int excl = incl - v;
    int slot = v ? excl : (nValid + (t - excl));
    order[slot] = t;
  }
  __syncthreads();

  // ---- phase 5: ordered points + ordv into LDS
  if (t < KTOP){
    int p = order[t];
    pts[t] = make_float2(xo[p], yo[p]);
    ordvl[t] = (u32)p | ((u32)vld[p] << 31);
  } else if (t < 512){
    pts[t] = make_float2(1e30f, 1e30f);
    ordvl[t] = 0u;
  }
  __syncthreads();

  // ---- phase 6: greedy kept-set scan (wave 0 only; kept set in lane regs)
  if (t < 64){
    int nv = nValid;
    float kx0 = 1e30f, ky0 = 1e30f, kx1 = 1e30f, ky1 = 1e30f;
    int count = 0;
    u64 curw = 0ull;
    int i = 0;
    float2 pcur = pts[0];
    float2 pnxt = pts[1];
    for (i = 0; i < nv; ++i){
      float2 p = pcur;
      pcur = pnxt;
      pnxt = pts[(i + 2 < 512) ? (i + 2) : 511];   // prefetch 2 ahead
      float dx0 = __fsub_rn(kx0, p.x), dy0 = __fsub_rn(ky0, p.y);
      float dx1 = __fsub_rn(kx1, p.x), dy1 = __fsub_rn(ky1, p.y);
      float d20 = __fadd_rn(__fmul_rn(dx0,dx0), __fmul_rn(dy0,dy0));
      float d21 = __fadd_rn(__fmul_rn(dx1,dx1), __fmul_rn(dy1,dy1));
      bool nearby = (d20 <= 4.0f) || (d21 <= 4.0f);
      if (!__any(nearby)){
        // keep candidate i: append (uniform) point to lane #count's registers
        curw |= (1ull << (i & 63));
        if (count < 64){
          if (t == count){ kx0 = p.x; ky0 = p.y; }
        } else {
          if (t == count - 64){ kx1 = p.x; ky1 = p.y; }
        }
        ++count;
        if (count == POST_MAX) break;   // cap: later entries can never be kept
      }
      if ((i & 63) == 63){
        if (t == 0) keepw[i >> 6] |= curw;
        curw = 0ull;
      }
    }
    if (t == 0 && curw != 0ull){
      int wi = i >> 6; if (wi > 7) wi = 7;
      keepw[wi] |= curw;
    }
  }
  __syncthreads();

  // ---- phase 7: keep-write
  if (t < KTOP){
    int bit = (int)((keepw[t >> 6] >> (t & 63)) & 1ull);
    u32 pv = ordvl[t];
    int p = (int)(pv & 511u);
    out[48000 + b*KTOP + p] = (bit && (pv >> 31)) ? 1.0f : 0.0f;
  }
}

extern "C" void kernel_launch(void* const* d_in, const int* in_sizes, int n_in,
                              void* d_out, int out_size, void* d_ws, size_t ws_size,
                              hipStream_t stream){
  const float* heat = (const float*)d_in[0];
  const float* reg  = (const float*)d_in[1];
  const float* rots = (const float*)d_in[2];
  const float* rotc = (const float*)d_in[3];
  const float* hei  = (const float*)d_in[4];
  const float* dim  = (const float*)d_in[5];
  const float* vel  = (const float*)d_in[6];
  float* out = (float*)d_out;
  char* ws = (char*)d_ws;
  u32*   cnt2 = (u32*)  (ws + WS_CNT2);
  uint2* cand = (uint2*)(ws + WS_CAND);

  k1_collect <<<2048, 256, 0, stream>>>(heat, cnt2, cand);
  kT_tail    <<<8,   1024, 0, stream>>>(heat, cnt2, cand, reg, rots, rotc, hei, dim, vel, out);
}

// Round 13
// 54.075 us; speedup vs baseline: 1.2610x; 1.2610x over previous
//
#include <hip/hip_runtime.h>
#include <stdint.h>

typedef unsigned int u32;
typedef unsigned long long u64;

#define HW (1024*1024)
#define KTOP 500
#define CAP 8192u
#define POST_MAX 83
#define DELTA_THR 9728u     // v > 1 - 9728*2^-24 ~ 0.99942; E[count/slice] ~ 580

// workspace byte offsets
#define WS_CNT2  0          // u32[16*128] = 8 KB (every slot written every run)
#define WS_CAND  32768      // uint2[16*8192] -> ends 1081344
#define WS_SORT  1081344    // uint2[16*512] -> ends 1146880

// out layout (floats): boxes[0,36000) scores[36000,40000) clses[40000,44000)
// valid[44000,48000) keep[48000,52000)

// ---------------- K1: streaming collect, fixed per-chunk slots, NO atomics ---
__global__ __launch_bounds__(256) void k1_collect(const float* __restrict__ heat,
                                                  u32* cnt2, uint2* cand){
  __shared__ uint2 lbuf[64];
  __shared__ u32 lcnt;
  int s     = blockIdx.x >> 7;   // 16 slices x 128 chunks
  int chunk = blockIdx.x & 127;
  int tid   = threadIdx.x;
  if (tid == 0) lcnt = 0;
  __syncthreads();
  const float4* hp = (const float4*)(heat + (size_t)s*HW + (size_t)chunk*8192);
  float4 v[8];
  #pragma unroll
  for (int i = 0; i < 8; ++i) v[i] = hp[i*256 + tid];
  #pragma unroll
  for (int i = 0; i < 8; ++i){
    u32 idx0 = (u32)chunk*8192u + (u32)(i*256 + tid)*4u;
    float vals[4] = {v[i].x, v[i].y, v[i].z, v[i].w};
    #pragma unroll
    for (int c = 0; c < 4; ++c){
      u32 bits  = __float_as_uint(vals[c]);
      u32 delta = 0x3F800000u - bits;         // ulps below 1.0
      if (delta < DELTA_THR){                 // E ~ 4.8 per chunk
        u32 p = atomicAdd(&lcnt, 1u);         // LDS atomic only
        if (p < 64u) lbuf[p] = make_uint2(bits, idx0 + (u32)c);
      }
    }
  }
  __syncthreads();
  u32 n = lcnt;
  u32 stored = (n < 64u) ? n : 64u;
  if (tid < stored) cand[(size_t)s*CAP + (u32)chunk*64u + tid] = lbuf[tid];
  if (tid == 0) cnt2[s*128 + chunk] = stored | ((n > 64u) ? 0x80000000u : 0u);
}

// ---------------- KR: gather slots + exact top-500 via rank-by-count ---------
// 2 blocks per slice (each ranks half; both build the full key array).
__global__ __launch_bounds__(1024) void kR_rank(const float* __restrict__ heat,
                                                const u32* __restrict__ cnt2,
                                                uint2* cand, uint2* sorted){
  __shared__ __align__(16) u64 lkey[CAP];   // 64 KiB
  __shared__ u32 coff[129];
  __shared__ u32 lhist[256];
  __shared__ u32 lc;
  __shared__ int t2s;
  __shared__ u32 meta;
  int s = blockIdx.x >> 1, h = blockIdx.x & 1, t = threadIdx.x;

  if (t == 0){
    u32 tot = 0, ov = 0;
    for (int c = 0; c < 128; ++c){
      u32 w = cnt2[s*128 + c];
      ov |= (w >> 31);
      coff[c] = tot;
      tot += (w & 0x7FFFFFFFu);
    }
    coff[128] = tot;
    meta = tot | (ov << 31);
  }
  __syncthreads();
  u32 total = meta & 0x7FFFFFFFu;
  bool fb = ((meta >> 31) != 0u) || (total < (u32)KTOP);
  u32 n;

  if (!fb){
    n = total;
    // gather per-chunk runs into compact key array (value desc, idx asc)
    for (u32 i = t; i < CAP; i += 1024){
      u32 c = i >> 6, j = i & 63u;
      u32 cnt_c = coff[c+1] - coff[c];
      if (j < cnt_c){
        uint2 cv = cand[(size_t)s*CAP + i];
        lkey[coff[c] + j] = ((u64)(~cv.x) << 32) | (u64)cv.y;
      }
    }
    __syncthreads();
  } else {
    if (h) return;        // fallback handled entirely by block h==0
    // ---- exactness fallback (never taken on this data): hist + recollect ----
    if (t < 256) lhist[t] = 0;
    if (t == 0) lc = 0;
    __syncthreads();
    const float4* hp = (const float4*)(heat + (size_t)s*HW);
    for (int it = 0; it < 256; ++it){
      float4 v = hp[it*1024 + t];
      #pragma unroll
      for (int c = 0; c < 4; ++c){
        float val = (c==0)?v.x:(c==1)?v.y:(c==2)?v.z:v.w;
        u32 bits  = __float_as_uint(val);
        u32 delta = 0x3F800000u - bits;
        u32 bin   = delta >> 16; if (bin > 255u) bin = 255u;
        atomicAdd(&lhist[bin], 1u);
      }
    }
    __syncthreads();
    if (t == 0){
      u32 cum = 0; u32 b1 = 255u;
      for (u32 bb = 0; bb < 256u; ++bb){
        cum += lhist[bb];
        if (cum >= (u32)KTOP){ b1 = bb; break; }
      }
      t2s = (int)(0x3F800000u - ((b1 + 1u) << 16) + 1u);
    }
    __syncthreads();
    int t2 = t2s;
    for (int it = 0; it < 256; ++it){
      float4 v = hp[it*1024 + t];
      u32 idx0 = (u32)(it*1024 + t)*4u;
      #pragma unroll
      for (int c = 0; c < 4; ++c){
        float val = (c==0)?v.x:(c==1)?v.y:(c==2)?v.z:v.w;
        int bits = (int)__float_as_uint(val);   // signed cmp excludes negatives
        if (bits >= t2){
          u32 p = atomicAdd(&lc, 1u);
          if (p < CAP) cand[(size_t)s*CAP + p] = make_uint2((u32)bits, idx0 + (u32)c);
        }
      }
    }
    __syncthreads();
    n = (lc < CAP) ? lc : CAP;
    for (u32 i = t; i < n; i += 1024){
      uint2 cv = cand[(size_t)s*CAP + i];
      lkey[i] = ((u64)(~cv.x) << 32) | (u64)cv.y;
    }
    __syncthreads();
  }

  // ---- rank-by-count over this block's range: rank = #{key' < key} ----------
  // inner loop manually unrolled 8x (16 keys / iter): 8 independent
  // ds_read_b128 issued back-to-back -> latency amortized ~8x.
  u32 lo = fb ? 0u : (u32)h * ((n + 1u) >> 1);
  u32 hi = fb ? n  : (h ? n : ((n + 1u) >> 1));
  const ulonglong2* lk2 = (const ulonglong2*)lkey;
  u32 np  = n >> 1;            // number of ulonglong2 pairs
  u32 np8 = np & ~7u;
  for (u32 me = lo + t; me < hi; me += 1024){
    u64 k0 = lkey[me];
    u32 r = 0;
    u32 j = 0;
    for (; j < np8; j += 8){
      ulonglong2 a0 = lk2[j+0];
      ulonglong2 a1 = lk2[j+1];
      ulonglong2 a2 = lk2[j+2];
      ulonglong2 a3 = lk2[j+3];
      ulonglong2 a4 = lk2[j+4];
      ulonglong2 a5 = lk2[j+5];
      ulonglong2 a6 = lk2[j+6];
      ulonglong2 a7 = lk2[j+7];
      r += (a0.x < k0) + (a0.y < k0) + (a1.x < k0) + (a1.y < k0);
      r += (a2.x < k0) + (a2.y < k0) + (a3.x < k0) + (a3.y < k0);
      r += (a4.x < k0) + (a4.y < k0) + (a5.x < k0) + (a5.y < k0);
      r += (a6.x < k0) + (a6.y < k0) + (a7.x < k0) + (a7.y < k0);
    }
    for (; j < np; ++j){
      ulonglong2 kk = lk2[j];
      r += (kk.x < k0) + (kk.y < k0);
    }
    if (n & 1u) r += (lkey[n-1] < k0) ? 1u : 0u;
    if (r < 512u)
      sorted[s*512 + (int)r] = make_uint2(~(u32)(k0 >> 32), (u32)k0);
  }
}

// ---------------- KT: merge + decode + partition + greedy NMS ----------------
__global__ __launch_bounds__(1024) void kT_tail(const uint2* __restrict__ sorted,
                                                const float* __restrict__ reg,
                                                const float* __restrict__ rots,
                                                const float* __restrict__ rotc,
                                                const float* __restrict__ hei,
                                                const float* __restrict__ dim,
                                                const float* __restrict__ vel,
                                                float* out){
  __shared__ u64 k2a[512], k2b[512];
  __shared__ uint2 fin[512];           // .x=score bits, .y=idx | cls<<20
  __shared__ float xo[512], yo[512];
  __shared__ float2 pts[512];
  __shared__ int order[512], vld[512];
  __shared__ u32 ordvl[512];
  __shared__ int wsum[16];
  __shared__ u64 keepw[8];
  int b = blockIdx.x, t = threadIdx.x;

  // ---- phase 1: load both sorted lists, level-2 keys (score desc, concat-pos asc)
  uint2 mye = make_uint2(0u, 0u);
  if (t < 512){
    mye = sorted[(b*2 + 0)*512 + t];
    k2a[t] = ((u64)(~mye.x) << 32) | (u64)t;
  } else {
    int p = t - 512;
    mye = sorted[(b*2 + 1)*512 + p];
    k2b[p] = ((u64)(~mye.x) << 32) | (u64)(KTOP + p);
  }
  if (t < 8) keepw[t] = 0ull;
  __syncthreads();

  // ---- phase 2: merged rank = own rank + lower_bound in other list
  if (t < KTOP){
    u64 K = k2a[t];
    int lo = 0, hi = KTOP;
    while (lo < hi){ int mid = (lo + hi) >> 1; if (k2b[mid] < K) lo = mid + 1; else hi = mid; }
    int m = t + lo;
    if (m < KTOP){
      fin[m] = make_uint2(mye.x, mye.y & 0xFFFFFu);
      out[36000 + b*KTOP + m] = __uint_as_float(mye.x);
      out[40000 + b*KTOP + m] = 0.0f;
    }
  } else if (t >= 512 && t < 512 + KTOP){
    int p = t - 512;
    u64 K = k2b[p];
    int lo = 0, hi = KTOP;
    while (lo < hi){ int mid = (lo + hi) >> 1; if (k2a[mid] < K) lo = mid + 1; else hi = mid; }
    int m = p + lo;
    if (m < KTOP){
      fin[m] = make_uint2(mye.x, (mye.y & 0xFFFFFu) | (1u << 20));
      out[36000 + b*KTOP + m] = __uint_as_float(mye.x);
      out[40000 + b*KTOP + m] = 1.0f;
    }
  }
  __syncthreads();

  // ---- phase 3: gather + decode + valid
  float x = 0.f, y = 0.f; int v = 0;
  if (t < KTOP){
    uint2 e = fin[t];
    u32 ind = e.y & 0xFFFFFu;
    float mysc = __uint_as_float(e.x);
    float xs0 = (float)(ind & 1023u);
    float ys0 = (float)(ind >> 10);
    size_t bb = (size_t)b;
    float r0  = reg [(bb*2 + 0)*HW + ind];
    float r1  = reg [(bb*2 + 1)*HW + ind];
    float sn  = rots[ bb       *HW + ind];
    float cs  = rotc[ bb       *HW + ind];
    float he  = hei [ bb       *HW + ind];
    float d0  = dim [(bb*3 + 0)*HW + ind];
    float d1  = dim [(bb*3 + 1)*HW + ind];
    float d2v = dim [(bb*3 + 2)*HW + ind];
    float v0  = vel [(bb*2 + 0)*HW + ind];
    float v1  = vel [(bb*2 + 1)*HW + ind];
    x = xs0 + r0; y = ys0 + r1;
    float rot = atan2f(sn, cs);
    float* bx = out + (size_t)(b*KTOP + t)*9;
    bx[0]=x; bx[1]=y; bx[2]=he; bx[3]=d0; bx[4]=d1; bx[5]=d2v; bx[6]=rot; bx[7]=v0; bx[8]=v1;
    v = ((x >= -100.0f) && (x <= 1124.0f) &&
         (y >= -100.0f) && (y <= 1124.0f) &&
         (he >= -10.0f) && (he <= 10.0f) && (mysc > 0.1f)) ? 1 : 0;
    out[44000 + b*KTOP + t] = v ? 1.0f : 0.0f;
  }
  if (t < 512){ xo[t] = x; yo[t] = y; vld[t] = v; }

  // ---- phase 4: 1-barrier ballot scan, stable valid-first partition
  u64 bm = __ballot(v != 0);
  int lane = t & 63, wv = t >> 6;
  if (lane == 0) wsum[wv] = __popcll(bm);
  __syncthreads();
  int off = 0, nValid = 0;
  #pragma unroll
  for (int w2 = 0; w2 < 8; ++w2){
    int sv = wsum[w2];
    nValid += sv;
    if (w2 < wv) off += sv;
  }
  int incl = off + __popcll(bm & ((~0ull) >> (63 - lane)));
  if (t < KTOP){
    int excl = incl - v;
    int slot = v ? excl : (nValid + (t - excl));
    order[slot] = t;
  }
  __syncthreads();

  // ---- phase 5: ordered points + ordv into LDS
  if (t < KTOP){
    int p = order[t];
    pts[t] = make_float2(xo[p], yo[p]);
    ordvl[t] = (u32)p | ((u32)vld[p] << 31);
  } else if (t < 512){
    pts[t] = make_float2(1e30f, 1e30f);
    ordvl[t] = 0u;
  }
  __syncthreads();

  // ---- phase 6: greedy kept-set scan (wave 0 only; kept set in lane regs)
  if (t < 64){
    int nv = nValid;
    float kx0 = 1e30f, ky0 = 1e30f, kx1 = 1e30f, ky1 = 1e30f;
    int count = 0;
    u64 curw = 0ull;
    int i = 0;
    float2 pcur = pts[0];
    float2 pnxt = pts[1];
    for (i = 0; i < nv; ++i){
      float2 p = pcur;
      pcur = pnxt;
      pnxt = pts[(i + 2 < 512) ? (i + 2) : 511];   // prefetch 2 ahead
      float dx0 = __fsub_rn(kx0, p.x), dy0 = __fsub_rn(ky0, p.y);
      float dx1 = __fsub_rn(kx1, p.x), dy1 = __fsub_rn(ky1, p.y);
      float d20 = __fadd_rn(__fmul_rn(dx0,dx0), __fmul_rn(dy0,dy0));
      float d21 = __fadd_rn(__fmul_rn(dx1,dx1), __fmul_rn(dy1,dy1));
      bool nearby = (d20 <= 4.0f) || (d21 <= 4.0f);
      if (!__any(nearby)){
        // keep candidate i: append (uniform) point to lane #count's registers
        curw |= (1ull << (i & 63));
        if (count < 64){
          if (t == count){ kx0 = p.x; ky0 = p.y; }
        } else {
          if (t == count - 64){ kx1 = p.x; ky1 = p.y; }
        }
        ++count;
        if (count == POST_MAX) break;   // cap: later entries can never be kept
      }
      if ((i & 63) == 63){
        if (t == 0) keepw[i >> 6] |= curw;
        curw = 0ull;
      }
    }
    if (t == 0 && curw != 0ull){
      int wi = i >> 6; if (wi > 7) wi = 7;
      keepw[wi] |= curw;
    }
  }
  __syncthreads();

  // ---- phase 7: keep-write
  if (t < KTOP){
    int bit = (int)((keepw[t >> 6] >> (t & 63)) & 1ull);
    u32 pv = ordvl[t];
    int p = (int)(pv & 511u);
    out[48000 + b*KTOP + p] = (bit && (pv >> 31)) ? 1.0f : 0.0f;
  }
}

extern "C" void kernel_launch(void* const* d_in, const int* in_sizes, int n_in,
                              void* d_out, int out_size, void* d_ws, size_t ws_size,
                              hipStream_t stream){
  const float* heat = (const float*)d_in[0];
  const float* reg  = (const float*)d_in[1];
  const float* rots = (const float*)d_in[2];
  const float* rotc = (const float*)d_in[3];
  const float* hei  = (const float*)d_in[4];
  const float* dim  = (const float*)d_in[5];
  const float* vel  = (const float*)d_in[6];
  float* out = (float*)d_out;
  char* ws = (char*)d_ws;
  u32*   cnt2   = (u32*)  (ws + WS_CNT2);
  uint2* cand   = (uint2*)(ws + WS_CAND);
  uint2* sorted = (uint2*)(ws + WS_SORT);

  k1_collect <<<2048, 256, 0, stream>>>(heat, cnt2, cand);
  kR_rank    <<<32,  1024, 0, stream>>>(heat, cnt2, cand, sorted);
  kT_tail    <<<8,   1024, 0, stream>>>(sorted, reg, rots, rotc, hei, dim, vel, out);
}